// Round 2
// baseline (488.527 us; speedup 1.0000x reference)
//
#include <hip/hip_runtime.h>
#include <cstdint>
#include <cstddef>

#define NTOK 2048
#define DIMSZ 512
#define NH 8
#define DH 64

typedef __attribute__((ext_vector_type(8))) short bf16x8;
typedef __attribute__((ext_vector_type(4))) float f32x4;

__device__ __forceinline__ short f2bf(float f) {
  uint32_t u = __float_as_uint(f);
  u += 0x7fffu + ((u >> 16) & 1u);   // RNE
  return (short)(u >> 16);
}

// ---------------------------------------------------------------------------
// Kernel 1: fused triple projection GEMM, bf16 MFMA.
//   P = epilogue(A @ W^T + b), A [2048,512] f32 row-major, W [512,512] f32.
//   blockIdx.z selects (query,Wq,bq)->Q(elu+1), (key,Wk,bk)->K(elu+1),
//   (value,Wv,bv)->V(raw).
//   R2: tile 128x128 -> 64x64. Old grid was 192 blocks on 256 CUs = 1
//   wave/SIMD -> staging latency fully exposed. New grid 8x32x3 = 768
//   blocks = 3 blocks/CU = 12 waves/CU; acc shrinks to [2][2] (16 VGPR).
//   Block 256 thr = 4 waves (2x2), wave tile 32x32, BK=32, 16x16x32 MFMA.
// ---------------------------------------------------------------------------
#define LDSS 40  // padded LDS row stride in shorts (32 + 8)

__global__ __launch_bounds__(256) void proj_kernel(
    const float* __restrict__ query, const float* __restrict__ keyi,
    const float* __restrict__ val,
    const float* __restrict__ Wq, const float* __restrict__ bq,
    const float* __restrict__ Wk, const float* __restrict__ bk,
    const float* __restrict__ Wv, const float* __restrict__ bv,
    float* __restrict__ Qp, float* __restrict__ Kp, float* __restrict__ Vp)
{
  const float* A; const float* W; const float* bias; float* P; bool do_elu;
  if (blockIdx.z == 0)      { A = query; W = Wq; bias = bq; P = Qp; do_elu = true; }
  else if (blockIdx.z == 1) { A = keyi;  W = Wk; bias = bk; P = Kp; do_elu = true; }
  else                      { A = val;   W = Wv; bias = bv; P = Vp; do_elu = false; }

  __shared__ short Ash[64 * LDSS];
  __shared__ short Wsh[64 * LDSS];

  const int tid  = threadIdx.x;
  const int lane = tid & 63;
  const int wave = tid >> 6;
  const int l15  = lane & 15;
  const int quad = lane >> 4;
  const int waveM = wave >> 1;  // 0..1
  const int waveN = wave & 1;   // 0..1

  const int rowBase = blockIdx.y * 64;
  const int colBase = blockIdx.x * 64;

  f32x4 acc[2][2] = {};

  const int sRow = tid >> 3;        // 0..31
  const int sCol = (tid & 7) * 4;   // 0..28

  for (int k0 = 0; k0 < DIMSZ; k0 += 32) {
#pragma unroll
    for (int rr = 0; rr < 2; ++rr) {
      const int r = sRow + rr * 32;
      float4 va = *(const float4*)&A[(size_t)(rowBase + r) * DIMSZ + k0 + sCol];
      short4 sa = make_short4(f2bf(va.x), f2bf(va.y), f2bf(va.z), f2bf(va.w));
      *(short4*)&Ash[r * LDSS + sCol] = sa;
      float4 vw = *(const float4*)&W[(size_t)(colBase + r) * DIMSZ + k0 + sCol];
      short4 sw = make_short4(f2bf(vw.x), f2bf(vw.y), f2bf(vw.z), f2bf(vw.w));
      *(short4*)&Wsh[r * LDSS + sCol] = sw;
    }
    __syncthreads();

    bf16x8 afrag[2], bfrag[2];
#pragma unroll
    for (int mi = 0; mi < 2; ++mi) {
      const int m = waveM * 32 + mi * 16 + l15;
      afrag[mi] = *(const bf16x8*)&Ash[m * LDSS + quad * 8];
    }
#pragma unroll
    for (int ni = 0; ni < 2; ++ni) {
      const int n = waveN * 32 + ni * 16 + l15;
      bfrag[ni] = *(const bf16x8*)&Wsh[n * LDSS + quad * 8];
    }
#pragma unroll
    for (int mi = 0; mi < 2; ++mi)
#pragma unroll
      for (int ni = 0; ni < 2; ++ni)
        acc[mi][ni] = __builtin_amdgcn_mfma_f32_16x16x32_bf16(
            afrag[mi], bfrag[ni], acc[mi][ni], 0, 0, 0);
    __syncthreads();
  }

  // Epilogue: C/D layout col = lane&15, row = quad*4 + reg  [measured m89/m91]
#pragma unroll
  for (int mi = 0; mi < 2; ++mi) {
#pragma unroll
    for (int ni = 0; ni < 2; ++ni) {
      const int gcol = colBase + waveN * 32 + ni * 16 + l15;
      const float b = bias[gcol];
#pragma unroll
      for (int r = 0; r < 4; ++r) {
        const int grow = rowBase + waveM * 32 + mi * 16 + quad * 4 + r;
        float y = acc[mi][ni][r] + b;
        if (do_elu) y = (y > 0.0f) ? (y + 1.0f) : __expf(y);  // elu(y)+1
        P[(size_t)grow * DIMSZ + gcol] = y;
      }
    }
  }
}

// ---------------------------------------------------------------------------
// Kernel 2: stream Si, apply state update + output contraction.
//   One wave per (n,h). lane = g*16 + l:  l -> columns m=4l..4l+3,
//   g -> d in {g, g+4, ..., g+60}. Fully coalesced 1KiB/wave float4 Si
//   load+store, nontemporal on the 540 MB streaming path.
//   R2: full 16-deep preload (both 8-batches issued back-to-back) -> one
//   contiguous 16 KB/wave read burst in flight before any store traffic.
// ---------------------------------------------------------------------------
__global__ __launch_bounds__(256) void stream_kernel(
    const float* __restrict__ Si, const float* __restrict__ Zi,
    const float* __restrict__ Qp, const float* __restrict__ Kp,
    const float* __restrict__ Vp,
    float* __restrict__ out, float* __restrict__ si_out,
    float* __restrict__ zi_out)
{
  const int wave = threadIdx.x >> 6;
  const int lane = threadIdx.x & 63;
  const int pair = blockIdx.x * 4 + wave;  // 0..16383 = n*8 + h
  const int n = pair >> 3;
  const int h = pair & 7;
  const int l = lane & 15;
  const int g = lane >> 4;

  const int    qkv_off = n * DIMSZ + h * DH;
  const int    zi_off  = pair * DH;
  const size_t si_off  = (size_t)pair * (DH * DH);

  const float4 q4  = *(const float4*)&Qp[qkv_off + l * 4];
  const float4 k4  = *(const float4*)&Kp[qkv_off + l * 4];
  const float4 v4  = *(const float4*)&Vp[qkv_off + l * 4];
  const float4 zi4 = *(const float4*)&Zi[zi_off + l * 4];

  f32x4 zin4;
  zin4.x = zi4.x + k4.x; zin4.y = zi4.y + k4.y;
  zin4.z = zi4.z + k4.z; zin4.w = zi4.w + k4.w;
  if (g == 0)
    __builtin_nontemporal_store(zin4, (f32x4*)&zi_out[zi_off + l * 4]);

  // z = 1/(Q . Zi_new + eps): partial over this lane's 4 elems, butterfly
  // over the 16-lane group (groups replicate the same data).
  float p = q4.x * zin4.x + q4.y * zin4.y + q4.z * zin4.z + q4.w * zin4.w;
  p += __shfl_xor(p, 1);
  p += __shfl_xor(p, 2);
  p += __shfl_xor(p, 4);
  p += __shfl_xor(p, 8);
  const float z = 1.0f / (p + 1e-6f);

  float qd[16], kd[16];
#pragma unroll
  for (int i = 0; i < 16; ++i) {
    const int d = i * 4 + g;
    qd[i] = Qp[qkv_off + d];
    kd[i] = Kp[qkv_off + d];
  }

  // Per-wave base of the Si panel: row d = g, cols l*4..l*4+3.
  // Iteration i advances d by 4 -> +256 floats.
  const float* sip = &Si[si_off + (size_t)g * DH + l * 4];
  float*       sop = &si_out[si_off + (size_t)g * DH + l * 4];

  f32x4 s[16];
#pragma unroll
  for (int i = 0; i < 16; ++i)
    s[i] = __builtin_nontemporal_load((const f32x4*)(sip + (size_t)i * 256));

  float a0 = 0.f, a1 = 0.f, a2 = 0.f, a3 = 0.f;
#pragma unroll
  for (int i = 0; i < 16; ++i) {
    f32x4 sn;
    sn.x = s[i].x + kd[i] * v4.x;
    sn.y = s[i].y + kd[i] * v4.y;
    sn.z = s[i].z + kd[i] * v4.z;
    sn.w = s[i].w + kd[i] * v4.w;
    __builtin_nontemporal_store(sn, (f32x4*)(sop + (size_t)i * 256));
    a0 += qd[i] * sn.x;
    a1 += qd[i] * sn.y;
    a2 += qd[i] * sn.z;
    a3 += qd[i] * sn.w;
  }

  // reduce partial out over the 4 d-groups
  a0 += __shfl_xor(a0, 16); a0 += __shfl_xor(a0, 32);
  a1 += __shfl_xor(a1, 16); a1 += __shfl_xor(a1, 32);
  a2 += __shfl_xor(a2, 16); a2 += __shfl_xor(a2, 32);
  a3 += __shfl_xor(a3, 16); a3 += __shfl_xor(a3, 32);

  if (g == 0) {
    float4 o;
    o.x = a0 * z; o.y = a1 * z; o.z = a2 * z; o.w = a3 * z;
    *(float4*)&out[(size_t)n * DIMSZ + h * DH + l * 4] = o;
  }
}

// ---------------------------------------------------------------------------
extern "C" void kernel_launch(void* const* d_in, const int* in_sizes, int n_in,
                              void* d_out, int out_size, void* d_ws, size_t ws_size,
                              hipStream_t stream) {
  const float* query = (const float*)d_in[0];
  const float* key_  = (const float*)d_in[1];
  const float* value = (const float*)d_in[2];
  const float* Si    = (const float*)d_in[3];
  const float* Zi    = (const float*)d_in[4];
  const float* Wq    = (const float*)d_in[5];
  const float* bq    = (const float*)d_in[6];
  const float* Wk    = (const float*)d_in[7];
  const float* bk    = (const float*)d_in[8];
  const float* Wv    = (const float*)d_in[9];
  const float* bv    = (const float*)d_in[10];

  float* out    = (float*)d_out;
  float* si_out = out + (size_t)NTOK * DIMSZ;                   // 1,048,576
  float* zi_out = si_out + (size_t)NTOK * NH * DH * DH;         // +67,108,864

  float* Qp = (float*)d_ws;                 // 3 x 4 MB scratch
  float* Kp = Qp + (size_t)NTOK * DIMSZ;
  float* Vp = Kp + (size_t)NTOK * DIMSZ;

  dim3 g1(DIMSZ / 64, NTOK / 64, 3);        // 8 x 32 x 3 = 768 blocks
  proj_kernel<<<g1, 256, 0, stream>>>(query, key_, value, Wq, bq, Wk, bk,
                                      Wv, bv, Qp, Kp, Vp);

  stream_kernel<<<NTOK * NH / 4, 256, 0, stream>>>(Si, Zi, Qp, Kp, Vp,
                                                   out, si_out, zi_out);
}